// Round 7
// baseline (46.913 us; speedup 1.0000x reference)
//
#include <hip/hip_runtime.h>
#include <math.h>

// ---------------- workspace layout (float offsets) ----------------
// P2 : 32 * 8 * 196 = 50176  (per (n, c-chunk) partial small masks)
#define P2_OFF 0

// Fused: per-block column-sum chunk of conv_w + channel dot at 14x14.
// grid (32 n, 8 cc) x 256 threads.
// wsum[c] = sum_o conv_w[o][c]; 1x1-conv + channel-mean commute; the 1/C
// factor and conv_b drop out of the min-max norm entirely.
__global__ void k_mask_small(const float* __restrict__ emb,
                             const float* __restrict__ conv_w,
                             float* __restrict__ ws) {
    __shared__ float wpart[256];
    __shared__ float wl[64];
    int n  = blockIdx.x;   // 0..31
    int cc = blockIdx.y;   // 0..7
    int t  = threadIdx.x;  // 0..255

    int col = t & 63, rg = t >> 6;
    float a = 0.f;
    const float* wp = conv_w + (rg * 64) * 512 + cc * 64 + col;
#pragma unroll 8
    for (int k = 0; k < 64; ++k) a += wp[k * 512];
    wpart[t] = a;
    __syncthreads();
    if (t < 64) wl[t] = wpart[t] + wpart[t + 64] + wpart[t + 128] + wpart[t + 192];
    __syncthreads();

    if (t < 196) {
        const float* base = emb + (size_t)(n * 512 + cc * 64) * 196 + t;
        float acc = 0.f;
#pragma unroll 8
        for (int c = 0; c < 64; ++c) acc += base[c * 196] * wl[c];
        ws[P2_OFF + (n * 8 + cc) * 196 + t] = acc;
    }
}

// Fused big pass: out = sigmoid(x) * (mask*weight + 1), mask in-register.
// grid (49 seg, 32 n) x 256 threads; each block owns 4096 contiguous float4
// of one sample (16 iters). 1568 blocks x 4 waves = 24.5 waves/CU -> the
// WHOLE grid is co-resident: prologue (LDS fill + redundant min/max sweep)
// runs once, fully parallel, no dispatch tail.
// Sweep uses incremental h/w tracking (no div/mod). Identical sweep order in
// every block -> identical (a,b); deterministic.
__global__ void __launch_bounds__(256) k_final(const float4* __restrict__ x4,
                                               const float* __restrict__ ws,
                                               const float* __restrict__ wgt_p,
                                               float4* __restrict__ out4) {
    __shared__ float sm[196];
    __shared__ float wred[8];
    const int t = threadIdx.x;
    const int s = blockIdx.x;          // 0..48  segment
    const int n = blockIdx.y;          // 0..31  sample

    const long base = (long)n * 200704 + (long)s * 4096;
    const float4* xp = x4   + base;
    float4*       op = out4 + base;

    float wgt = wgt_p[0];

    if (t < 196) {
        float a = 0.f;
#pragma unroll
        for (int k = 0; k < 8; ++k) a += ws[P2_OFF + (n * 8 + k) * 196 + t];
        sm[t] = a;
    }
    __syncthreads();

    // min/max over the upsampled 56x56 plane (reference bilinear form).
    // h,w tracked incrementally: +256 px == h+=4, w+=32 (mod 56).
    float vmin = INFINITY, vmax = -INFINITY;
    {
        int h = (t * 1171) >> 16;      // t/56 for t<256
        int w = t - h * 56;
        for (int p = t; p < 3136; p += 256) {
            float sy = h * 0.25f - 0.375f;
            float sx = w * 0.25f - 0.375f;
            int y0 = (int)floorf(sy); float fy = sy - (float)y0;
            int x0 = (int)floorf(sx); float fx = sx - (float)x0;
            int y1 = min(y0 + 1, 13); y0 = max(y0, 0);
            int x1 = min(x0 + 1, 13); x0 = max(x0, 0);
            float v00 = sm[y0 * 14 + x0], v01 = sm[y0 * 14 + x1];
            float v10 = sm[y1 * 14 + x0], v11 = sm[y1 * 14 + x1];
            float v = (1.f - fy) * ((1.f - fx) * v00 + fx * v01)
                    +        fy  * ((1.f - fx) * v10 + fx * v11);
            vmin = fminf(vmin, v);
            vmax = fmaxf(vmax, v);
            w += 32; h += 4;
            if (w >= 56) { w -= 56; h += 1; }
        }
    }
    // wave reduce (64 lanes), then one LDS hop across the 4 waves
#pragma unroll
    for (int off = 32; off > 0; off >>= 1) {
        vmin = fminf(vmin, __shfl_xor(vmin, off, 64));
        vmax = fmaxf(vmax, __shfl_xor(vmax, off, 64));
    }
    if ((t & 63) == 0) { wred[t >> 6] = vmin; wred[4 + (t >> 6)] = vmax; }
    __syncthreads();
    float mn = fminf(fminf(wred[0], wred[1]), fminf(wred[2], wred[3]));
    float mx = fmaxf(fmaxf(wred[4], wred[5]), fmaxf(wred[6], wred[7]));
    float a = wgt / (mx - mn);
    float b = 1.f - mn * a;

    // mask float4-phase of (base + t) in the 784-float4 plane: 4096%784==176
    const int q0 = (s * 176 + t) % 784;

#pragma unroll
    for (int i = 0; i < 16; ++i) {
        const int ci = (i * 256) % 784;   // compile-time constant
        int q = q0 + ci;
        if (q >= 784) q -= 784;           // q0+ci < 1568: one subtract
        int r  = (q * 4682) >> 16;        // q / 14  (valid for q < 784)
        int wq = q - r * 14;
        float sy = r * 0.25f - 0.375f;
        int y0 = (int)floorf(sy);
        float fy = sy - (float)y0;
        int y1 = min(y0 + 1, 13); y0 = max(y0, 0);
        int xm  = max(wq - 1, 0);
        int xp1 = min(wq + 1, 13);
        float t0 = sm[y0 * 14 + xm], t1 = sm[y0 * 14 + wq], t2 = sm[y0 * 14 + xp1];
        float b0 = sm[y1 * 14 + xm], b1 = sm[y1 * 14 + wq], b2 = sm[y1 * 14 + xp1];
        // column phases of the 4 pixels in this float4:
        // j=0: x0=wq-1, fx=.625  j=1: x0=wq-1, fx=.875
        // j=2: x0=wq,   fx=.125  j=3: x0=wq,   fx=.375
        float m0t = t0 + 0.625f * (t1 - t0), m0b = b0 + 0.625f * (b1 - b0);
        float m1t = t0 + 0.875f * (t1 - t0), m1b = b0 + 0.875f * (b1 - b0);
        float m2t = t1 + 0.125f * (t2 - t1), m2b = b1 + 0.125f * (b2 - b1);
        float m3t = t1 + 0.375f * (t2 - t1), m3b = b1 + 0.375f * (b2 - b1);
        float m0 = m0t + fy * (m0b - m0t);
        float m1 = m1t + fy * (m1b - m1t);
        float m2 = m2t + fy * (m2b - m2t);
        float m3 = m3t + fy * (m3b - m3t);

        float4 xi = xp[i * 256 + t];
        float4 o;
        o.x = (m0 * a + b) * __builtin_amdgcn_rcpf(1.f + __expf(-xi.x));
        o.y = (m1 * a + b) * __builtin_amdgcn_rcpf(1.f + __expf(-xi.y));
        o.z = (m2 * a + b) * __builtin_amdgcn_rcpf(1.f + __expf(-xi.z));
        o.w = (m3 * a + b) * __builtin_amdgcn_rcpf(1.f + __expf(-xi.w));
        op[i * 256 + t] = o;
    }
}

extern "C" void kernel_launch(void* const* d_in, const int* in_sizes, int n_in,
                              void* d_out, int out_size, void* d_ws, size_t ws_size,
                              hipStream_t stream) {
    const float* main_in = (const float*)d_in[0];  // [32,256,56,56]
    const float* emb_in  = (const float*)d_in[1];  // [32,512,14,14]
    const float* conv_w  = (const float*)d_in[2];  // [256,512]
    // d_in[3] = conv_b : provably dead (shift-invariant under min-max norm)
    const float* weight  = (const float*)d_in[4];  // scalar

    float* ws   = (float*)d_ws;
    float4* out = (float4*)d_out;

    k_mask_small<<<dim3(32, 8),  256, 0, stream>>>(emb_in, conv_w, ws);
    k_final     <<<dim3(49, 32), 256, 0, stream>>>((const float4*)main_in, ws, weight, out);
}

// Round 8
// 46.384 us; speedup vs baseline: 1.0114x; 1.0114x over previous
//
#include <hip/hip_runtime.h>
#include <math.h>

// ---------------- workspace layout (float offsets) ----------------
// P2 : 32 * 8 * 196 = 50176  (per (n, c-chunk) partial small masks)
#define P2_OFF 0

// Fused: per-block column-sum chunk of conv_w + channel dot at 14x14.
// grid (32 n, 8 cc) x 256 threads.
// wsum[c] = sum_o conv_w[o][c]; 1x1-conv + channel-mean commute; the 1/C
// factor and conv_b drop out of the min-max norm entirely.
__global__ void k_mask_small(const float* __restrict__ emb,
                             const float* __restrict__ conv_w,
                             float* __restrict__ ws) {
    __shared__ float wpart[256];
    __shared__ float wl[64];
    int n  = blockIdx.x;   // 0..31
    int cc = blockIdx.y;   // 0..7
    int t  = threadIdx.x;  // 0..255

    int col = t & 63, rg = t >> 6;
    float a = 0.f;
    const float* wp = conv_w + (rg * 64) * 512 + cc * 64 + col;
#pragma unroll 8
    for (int k = 0; k < 64; ++k) a += wp[k * 512];
    wpart[t] = a;
    __syncthreads();
    if (t < 64) wl[t] = wpart[t] + wpart[t + 64] + wpart[t + 128] + wpart[t + 192];
    __syncthreads();

    if (t < 196) {
        const float* base = emb + (size_t)(n * 512 + cc * 64) * 196 + t;
        float acc = 0.f;
#pragma unroll 8
        for (int c = 0; c < 64; ++c) acc += base[c * 196] * wl[c];
        ws[P2_OFF + (n * 8 + cc) * 196 + t] = acc;
    }
}

// Fused big pass: out = sigmoid(x) * (mask*weight + 1), mask in-register.
// grid (98 seg, 32 n) x 256 threads; each block owns 2048 contiguous float4
// of one sample. The 8 input float4s are prefetched FIRST; the mask prologue
// (LDS fill from L2-hot partials + redundant 3136-point min/max sweep) hides
// their HBM latency. Identical sweep order in every block -> identical (a,b);
// deterministic. Main loop: decode the 4 mask pixels of each float4 from the
// 14x14 LDS plane (fx pattern {.625,.875,.125,.375}, edge-clamped == jax
// half-pixel linear resize), then o = (v*a+b) * sigmoid(x).
__global__ void __launch_bounds__(256) k_final(const float4* __restrict__ x4,
                                               const float* __restrict__ ws,
                                               const float* __restrict__ wgt_p,
                                               float4* __restrict__ out4) {
    __shared__ float sm[196];
    __shared__ float wred[8];
    const int t = threadIdx.x;
    const int s = blockIdx.x;          // 0..97  segment
    const int n = blockIdx.y;          // 0..31  sample

    const long base = (long)n * 200704 + (long)s * 2048;
    const float4* xp = x4   + base;
    float4*       op = out4 + base;

    float wgt = wgt_p[0];

    // prefetch the 8 input float4s first; mask prologue hides their latency
    float4 x[8];
#pragma unroll
    for (int i = 0; i < 8; ++i) x[i] = xp[i * 256 + t];

    if (t < 196) {
        float a = 0.f;
#pragma unroll
        for (int k = 0; k < 8; ++k) a += ws[P2_OFF + (n * 8 + k) * 196 + t];
        sm[t] = a;
    }
    __syncthreads();

    // min/max over the upsampled 56x56 plane (reference bilinear form)
    float vmin = INFINITY, vmax = -INFINITY;
    for (int p = t; p < 3136; p += 256) {
        int h = p / 56, w = p % 56;
        float sy = (h + 0.5f) * 0.25f - 0.5f;
        float sx = (w + 0.5f) * 0.25f - 0.5f;
        int y0 = (int)floorf(sy); float fy = sy - (float)y0;
        int x0 = (int)floorf(sx); float fx = sx - (float)x0;
        int y1 = min(y0 + 1, 13); y0 = max(y0, 0);
        int x1 = min(x0 + 1, 13); x0 = max(x0, 0);
        float v00 = sm[y0 * 14 + x0], v01 = sm[y0 * 14 + x1];
        float v10 = sm[y1 * 14 + x0], v11 = sm[y1 * 14 + x1];
        float v = (1.f - fy) * ((1.f - fx) * v00 + fx * v01)
                +        fy  * ((1.f - fx) * v10 + fx * v11);
        vmin = fminf(vmin, v);
        vmax = fmaxf(vmax, v);
    }
    // wave reduce (64 lanes), then one LDS hop across the 4 waves
#pragma unroll
    for (int off = 32; off > 0; off >>= 1) {
        vmin = fminf(vmin, __shfl_xor(vmin, off, 64));
        vmax = fmaxf(vmax, __shfl_xor(vmax, off, 64));
    }
    if ((t & 63) == 0) { wred[t >> 6] = vmin; wred[4 + (t >> 6)] = vmax; }
    __syncthreads();
    float mn = fminf(fminf(wred[0], wred[1]), fminf(wred[2], wred[3]));
    float mx = fmaxf(fmaxf(wred[4], wred[5]), fmaxf(wred[6], wred[7]));
    float a = wgt / (mx - mn);
    float b = 1.f - mn * a;

    // mask float4-phase of (base + t) in the 784-float4 plane: 2048%784==480
    const int q0 = (s * 480 + t) % 784;

#pragma unroll
    for (int i = 0; i < 8; ++i) {
        const int ci = (i * 256) % 784;   // compile-time constant
        int q = q0 + ci;
        if (q >= 784) q -= 784;           // q0+ci < 1568: one subtract
        int r  = (q * 4682) >> 16;        // q / 14  (valid for q < 784)
        int wq = q - r * 14;
        float sy = r * 0.25f - 0.375f;
        int y0 = (int)floorf(sy);
        float fy = sy - (float)y0;
        int y1 = min(y0 + 1, 13); y0 = max(y0, 0);
        int xm  = max(wq - 1, 0);
        int xp1 = min(wq + 1, 13);
        float t0 = sm[y0 * 14 + xm], t1 = sm[y0 * 14 + wq], t2 = sm[y0 * 14 + xp1];
        float b0 = sm[y1 * 14 + xm], b1 = sm[y1 * 14 + wq], b2 = sm[y1 * 14 + xp1];
        // column phases of the 4 pixels in this float4:
        // j=0: x0=wq-1, fx=.625  j=1: x0=wq-1, fx=.875
        // j=2: x0=wq,   fx=.125  j=3: x0=wq,   fx=.375
        float m0t = t0 + 0.625f * (t1 - t0), m0b = b0 + 0.625f * (b1 - b0);
        float m1t = t0 + 0.875f * (t1 - t0), m1b = b0 + 0.875f * (b1 - b0);
        float m2t = t1 + 0.125f * (t2 - t1), m2b = b1 + 0.125f * (b2 - b1);
        float m3t = t1 + 0.375f * (t2 - t1), m3b = b1 + 0.375f * (b2 - b1);
        float m0 = m0t + fy * (m0b - m0t);
        float m1 = m1t + fy * (m1b - m1t);
        float m2 = m2t + fy * (m2b - m2t);
        float m3 = m3t + fy * (m3b - m3t);

        float4 xi = x[i];
        float4 o;
        o.x = (m0 * a + b) * __builtin_amdgcn_rcpf(1.f + __expf(-xi.x));
        o.y = (m1 * a + b) * __builtin_amdgcn_rcpf(1.f + __expf(-xi.y));
        o.z = (m2 * a + b) * __builtin_amdgcn_rcpf(1.f + __expf(-xi.z));
        o.w = (m3 * a + b) * __builtin_amdgcn_rcpf(1.f + __expf(-xi.w));
        op[i * 256 + t] = o;
    }
}

extern "C" void kernel_launch(void* const* d_in, const int* in_sizes, int n_in,
                              void* d_out, int out_size, void* d_ws, size_t ws_size,
                              hipStream_t stream) {
    const float* main_in = (const float*)d_in[0];  // [32,256,56,56]
    const float* emb_in  = (const float*)d_in[1];  // [32,512,14,14]
    const float* conv_w  = (const float*)d_in[2];  // [256,512]
    // d_in[3] = conv_b : provably dead (shift-invariant under min-max norm)
    const float* weight  = (const float*)d_in[4];  // scalar

    float* ws   = (float*)d_ws;
    float4* out = (float4*)d_out;

    k_mask_small<<<dim3(32, 8),  256, 0, stream>>>(emb_in, conv_w, ws);
    k_final     <<<dim3(98, 32), 256, 0, stream>>>((const float4*)main_in, ws, weight, out);
}